// Round 12
// baseline (96.283 us; speedup 1.0000x reference)
//
#include <hip/hip_runtime.h>
#include <hip/hip_bf16.h>
#include <stdint.h>

#define M_DIM 2048
#define N_DIM 4096
#define K_DIM 4096

#define BM 128
#define BN 256
#define BK 64

typedef __bf16 bf16x8 __attribute__((ext_vector_type(8)));
typedef float f32x4 __attribute__((ext_vector_type(4)));
typedef unsigned short ushort8_t __attribute__((ext_vector_type(8)));

__device__ __forceinline__ unsigned short f32_to_bf16_rne(float f) {
    union { float f; uint32_t u; } cvt;
    cvt.f = f;
    uint32_t u = cvt.u;
    uint32_t r = (u + 0x7fffu + ((u >> 16) & 1u)) >> 16;
    return (unsigned short)r;
}

__device__ __forceinline__ void gload_lds16(const void* g, void* l) {
    __builtin_amdgcn_global_load_lds(
        (__attribute__((address_space(1))) const void*)g,
        (__attribute__((address_space(3))) void*)l,
        16, 0, 0);
}

// ---------------------------------------------------------------------------
__global__ void convert_x_kernel(const float* __restrict__ x,
                                 unsigned short* __restrict__ xb, int n8) {
    int i = blockIdx.x * blockDim.x + threadIdx.x;
    int stride = gridDim.x * blockDim.x;
    for (; i < n8; i += stride) {
        const float4* p = (const float4*)(x + (size_t)i * 8);
        float4 v0 = p[0];
        float4 v1 = p[1];
        ushort8_t o;
        o[0] = f32_to_bf16_rne(v0.x);
        o[1] = f32_to_bf16_rne(v0.y);
        o[2] = f32_to_bf16_rne(v0.z);
        o[3] = f32_to_bf16_rne(v0.w);
        o[4] = f32_to_bf16_rne(v1.x);
        o[5] = f32_to_bf16_rne(v1.y);
        o[6] = f32_to_bf16_rne(v1.z);
        o[7] = f32_to_bf16_rne(v1.w);
        *(ushort8_t*)(xb + (size_t)i * 8) = o;
    }
}

// ---------------------------------------------------------------------------
__global__ void transpose_convert_w(const float* __restrict__ W,
                                    unsigned short* __restrict__ Wt) {
    __shared__ float tile[64][65];
    const int k0 = blockIdx.y * 64;
    const int n0 = blockIdx.x * 64;
    const int t  = threadIdx.x;
    const int tx = t & 15;
    const int ty = t >> 4;

#pragma unroll
    for (int r = 0; r < 4; ++r) {
        int row = ty + 16 * r;
        float4 v = *(const float4*)(W + (size_t)(k0 + row) * N_DIM + n0 + tx * 4);
        tile[row][tx * 4 + 0] = v.x;
        tile[row][tx * 4 + 1] = v.y;
        tile[row][tx * 4 + 2] = v.z;
        tile[row][tx * 4 + 3] = v.w;
    }
    __syncthreads();
#pragma unroll
    for (int r = 0; r < 4; ++r) {
        int nrow = ty + 16 * r;
        ushort4 o;
        o.x = f32_to_bf16_rne(tile[tx * 4 + 0][nrow]);
        o.y = f32_to_bf16_rne(tile[tx * 4 + 1][nrow]);
        o.z = f32_to_bf16_rne(tile[tx * 4 + 2][nrow]);
        o.w = f32_to_bf16_rne(tile[tx * 4 + 3][nrow]);
        *(ushort4*)(Wt + (size_t)(n0 + nrow) * K_DIM + k0 + tx * 4) = o;
    }
}

// ---------------------------------------------------------------------------
// GEMM: C[m][n] = sum_k A[m][k] * Bt[n][k] + bias[n]
// R9 geometry (128x256, 8 waves = 4 regions 64x128 x 2 kk-roles -> 2.67
// MFMA/read, triple buffer, 0-conflict swizzle, vmcnt(6) ledger, kk-combine
// epilogue) + m201/R7 DOUBLE-BARRIER PHASE DISCIPLINE:
//   per K-tile = 2 phases. Each phase:
//     {ds_read frags, stage 3 gloads, s_barrier, lgkmcnt(0)+sched_barrier,
//      setprio(1), 16 MFMA, setprio(0), s_barrier}
//   The 16-MFMA cluster drains through its closing barrier while the next
//   phase's read burst runs on the LDS pipe (~600-cyc overlap windows).
//   vmcnt(6) once per tile, before the tile's final barrier (never 0).
// Hazards: RAW buf tau+1 via vmcnt(6)+closing barrier; WAR stage target
// (tau+2)%3 == (tau-1)%3 via tile tau-1's P1 lgkm(0) before its closing
// barrier; rule-18 sched_barrier(0) after each asm wait.
// ---------------------------------------------------------------------------
__global__ __launch_bounds__(512, 2) void gemm_bf16(
    const unsigned short* __restrict__ A,
    const unsigned short* __restrict__ Bt,
    const float* __restrict__ bias,
    float* __restrict__ C) {
    __shared__ __align__(16) char smem[147456];
    // A bufs: smem + buf*16384           (3 x 16 KiB)
    // B bufs: smem + 49152 + buf*32768   (3 x 32 KiB)
    // epilogue partials: smem + region*32768 (4 x 32 KiB, after K-loop)

    const int t      = threadIdx.x;
    const int lane   = t & 63;
    const int wave   = t >> 6;
    const int region = wave >> 1;    // 0..3 : 64x128 output region
    const int kkr    = wave & 1;     // 0/1  : K-half role
    const int rm     = region >> 1;  // 0..1 row block (x64)
    const int rn     = region & 1;   // 0..1 col block (x128)
    const int lrow   = lane & 15;
    const int lhi    = lane >> 4;

    // T1: XCD-aware swizzle (256 WGs, %8==0 -> bijective)
    const int wg  = blockIdx.x;
    const int swz = (wg & 7) * 32 + (wg >> 3);
    const int m0  = (swz >> 4) * BM;
    const int n0  = (swz & 15) * BN;

    // staging: linear LDS dest + inverse-swizzled global source
    auto stageA = [&](int buf, int tile, int c) {
        int row = c >> 3, p = c & 7;
        int l   = p ^ (row & 7);
        gload_lds16(A + (size_t)(m0 + row) * K_DIM + tile * BK + l * 8,
                    smem + buf * 16384 + c * 16);
    };
    auto stageB = [&](int buf, int tile, int c) {
        int row = c >> 3, p = c & 7;
        int l   = p ^ (row & 7);
        gload_lds16(Bt + (size_t)(n0 + row) * K_DIM + tile * BK + l * 8,
                    smem + 49152 + buf * 32768 + c * 16);
    };

    f32x4 acc[4][8];  // [mi][nj], this wave's kk-half partial
#pragma unroll
    for (int i = 0; i < 4; ++i)
#pragma unroll
        for (int j = 0; j < 8; ++j) acc[i][j] = (f32x4)0.0f;

    const int NT = K_DIM / BK;  // 64

    // fragment offsets (row&7 == lrow&7; proven 0-conflict pattern)
    const int rowOffA = (rm * 64 + lrow) * 128;          // + mi*2048, mi 0..3
    const int rowOffB = (rn * 128 + lrow) * 128;         // + nj*2048, nj 0..7
    const int sK = ((kkr * 4 + lhi) ^ (lrow & 7)) * 16;  // this wave's kk slot

    // prologue: tiles 0 and 1 fully staged (12 chunks/thread in flight)
    stageA(0, 0, t); stageA(0, 0, t + 512);
    stageB(0, 0, t); stageB(0, 0, t + 512);
    stageB(0, 0, t + 1024); stageB(0, 0, t + 1536);
    stageA(1, 1, t); stageA(1, 1, t + 512);
    stageB(1, 1, t); stageB(1, 1, t + 512);
    stageB(1, 1, t + 1024); stageB(1, 1, t + 1536);

    // publish tile 0 (drains its 6 chunks; tile 1's 6 stay in flight)
    asm volatile("s_waitcnt vmcnt(6)" ::: "memory");
    __builtin_amdgcn_s_barrier();
    __builtin_amdgcn_sched_barrier(0);

    int bufC = 0, bufS = 2;
    for (int tau = 0; tau < NT; ++tau) {
        const int tile2 = (tau + 2 < NT) ? tau + 2 : NT - 1;
        const char* bA = smem + bufC * 16384;
        const char* bB = smem + 49152 + bufC * 32768;

        // ================= phase 0: nj 0..3 =================
        bf16x8 af[4], bh[4];
#pragma unroll
        for (int mi = 0; mi < 4; ++mi)
            af[mi] = *(const bf16x8*)(bA + rowOffA + mi * 2048 + sK);
#pragma unroll
        for (int nj = 0; nj < 4; ++nj)
            bh[nj] = *(const bf16x8*)(bB + rowOffB + nj * 2048 + sK);
        stageA(bufS, tile2, t);
        stageA(bufS, tile2, t + 512);
        stageB(bufS, tile2, t);

        __builtin_amdgcn_s_barrier();
        asm volatile("s_waitcnt lgkmcnt(0)" ::: "memory");
        __builtin_amdgcn_sched_barrier(0);

        __builtin_amdgcn_s_setprio(1);
#pragma unroll
        for (int mi = 0; mi < 4; ++mi)
#pragma unroll
            for (int nj = 0; nj < 4; ++nj)
                acc[mi][nj] = __builtin_amdgcn_mfma_f32_16x16x32_bf16(
                    af[mi], bh[nj], acc[mi][nj], 0, 0, 0);
        __builtin_amdgcn_s_setprio(0);
        __builtin_amdgcn_s_barrier();

        // ================= phase 1: nj 4..7 =================
        bf16x8 bg[4];
#pragma unroll
        for (int nj = 0; nj < 4; ++nj)
            bg[nj] = *(const bf16x8*)(bB + rowOffB + (nj + 4) * 2048 + sK);
        stageB(bufS, tile2, t + 512);
        stageB(bufS, tile2, t + 1024);
        stageB(bufS, tile2, t + 1536);

        __builtin_amdgcn_s_barrier();
        asm volatile("s_waitcnt lgkmcnt(0)" ::: "memory");
        __builtin_amdgcn_sched_barrier(0);

        __builtin_amdgcn_s_setprio(1);
#pragma unroll
        for (int mi = 0; mi < 4; ++mi)
#pragma unroll
            for (int nj = 0; nj < 4; ++nj)
                acc[mi][nj + 4] = __builtin_amdgcn_mfma_f32_16x16x32_bf16(
                    af[mi], bg[nj], acc[mi][nj + 4], 0, 0, 0);
        __builtin_amdgcn_s_setprio(0);

        // once per tile: publish buf tau+1 (drains tau-1's 6 staged chunks)
        asm volatile("s_waitcnt vmcnt(6)" ::: "memory");
        __builtin_amdgcn_s_barrier();
        __builtin_amdgcn_sched_barrier(0);

        bufC = (bufC == 2) ? 0 : bufC + 1;
        bufS = (bufS == 2) ? 0 : bufS + 1;
    }

    // ---- epilogue: combine kk pair via (dead) LDS, write C + bias ----
    __syncthreads();
    if (kkr == 1) {
#pragma unroll
        for (int mi = 0; mi < 4; ++mi)
#pragma unroll
            for (int nj = 0; nj < 8; ++nj)
                *(f32x4*)(smem + region * 32768 +
                          ((mi * 8 + nj) * 64 + lane) * 16) = acc[mi][nj];
    }
    __syncthreads();
    if (kkr == 0) {
        // C/D layout: col=lane&15, row=(lane>>4)*4+reg
#pragma unroll
        for (int nj = 0; nj < 8; ++nj) {
            int col  = n0 + rn * 128 + nj * 16 + lrow;
            float bv = bias[col];
#pragma unroll
            for (int mi = 0; mi < 4; ++mi) {
                f32x4 p = *(const f32x4*)(smem + region * 32768 +
                                          ((mi * 8 + nj) * 64 + lane) * 16);
                int rbase = m0 + rm * 64 + mi * 16 + lhi * 4;
#pragma unroll
                for (int r = 0; r < 4; ++r) {
                    C[(size_t)(rbase + r) * N_DIM + col] =
                        acc[mi][nj][r] + p[r] + bv;
                }
            }
        }
    }
}

// ---------------------------------------------------------------------------
extern "C" void kernel_launch(void* const* d_in, const int* in_sizes, int n_in,
                              void* d_out, int out_size, void* d_ws, size_t ws_size,
                              hipStream_t stream) {
    const float* x    = (const float*)d_in[0];
    const float* w    = (const float*)d_in[1];
    const float* bias = (const float*)d_in[2];
    float* out        = (float*)d_out;

    unsigned short* xb = (unsigned short*)d_ws;
    unsigned short* wt = (unsigned short*)((char*)d_ws +
                          (size_t)M_DIM * K_DIM * sizeof(unsigned short));

    convert_x_kernel<<<2048, 256, 0, stream>>>(x, xb, M_DIM * K_DIM / 8);

    dim3 tgrid(N_DIM / 64, K_DIM / 64);
    transpose_convert_w<<<tgrid, 256, 0, stream>>>(w, wt);

    dim3 ggrid((M_DIM / BM) * (N_DIM / BN));
    gemm_bf16<<<ggrid, 512, 0, stream>>>(xb, wt, bias, out);
}

// Round 13
// 89.866 us; speedup vs baseline: 1.0714x; 1.0714x over previous
//
#include <hip/hip_runtime.h>
#include <hip/hip_bf16.h>
#include <stdint.h>

#define M_DIM 2048
#define N_DIM 4096
#define K_DIM 4096

#define BM 128
#define BN 256
#define BK 64

typedef __bf16 bf16x8 __attribute__((ext_vector_type(8)));
typedef float f32x4 __attribute__((ext_vector_type(4)));
typedef unsigned short ushort8_t __attribute__((ext_vector_type(8)));

__device__ __forceinline__ unsigned short f32_to_bf16_rne(float f) {
    union { float f; uint32_t u; } cvt;
    cvt.f = f;
    uint32_t u = cvt.u;
    uint32_t r = (u + 0x7fffu + ((u >> 16) & 1u)) >> 16;
    return (unsigned short)r;
}

__device__ __forceinline__ void gload_lds16(const void* g, void* l) {
    __builtin_amdgcn_global_load_lds(
        (__attribute__((address_space(1))) const void*)g,
        (__attribute__((address_space(3))) void*)l,
        16, 0, 0);
}

// ---------------------------------------------------------------------------
// Fused prepass: blocks [0,4096) transpose+convert W (64x64 tiles);
// blocks [4096,6144) convert x f32->bf16. Both halves byte-identical to the
// proven standalone kernels; fusing removes one launch gap + dispatch tail.
// ---------------------------------------------------------------------------
__global__ void prep_kernel(const float* __restrict__ x,
                            unsigned short* __restrict__ xb,
                            const float* __restrict__ W,
                            unsigned short* __restrict__ Wt) {
    __shared__ float tile[64][65];
    const int b = blockIdx.x;
    const int t = threadIdx.x;

    if (b < 4096) {
        // ---- W (f32 [K][N]) -> Wt (bf16 [N][K]) ----
        const int n0 = (b & 63) * 64;
        const int k0 = (b >> 6) * 64;
        const int tx = t & 15;
        const int ty = t >> 4;

#pragma unroll
        for (int r = 0; r < 4; ++r) {
            int row = ty + 16 * r;
            float4 v = *(const float4*)(W + (size_t)(k0 + row) * N_DIM + n0 + tx * 4);
            tile[row][tx * 4 + 0] = v.x;
            tile[row][tx * 4 + 1] = v.y;
            tile[row][tx * 4 + 2] = v.z;
            tile[row][tx * 4 + 3] = v.w;
        }
        __syncthreads();
#pragma unroll
        for (int r = 0; r < 4; ++r) {
            int nrow = ty + 16 * r;
            ushort4 o;
            o.x = f32_to_bf16_rne(tile[tx * 4 + 0][nrow]);
            o.y = f32_to_bf16_rne(tile[tx * 4 + 1][nrow]);
            o.z = f32_to_bf16_rne(tile[tx * 4 + 2][nrow]);
            o.w = f32_to_bf16_rne(tile[tx * 4 + 3][nrow]);
            *(ushort4*)(Wt + (size_t)(n0 + nrow) * K_DIM + k0 + tx * 4) = o;
        }
    } else {
        // ---- x (f32 [M][K]) -> bf16 ----
        const int n8 = M_DIM * K_DIM / 8;
        int i = (b - 4096) * blockDim.x + t;
        const int stride = 2048 * 256;
        for (; i < n8; i += stride) {
            const float4* p = (const float4*)(x + (size_t)i * 8);
            float4 v0 = p[0];
            float4 v1 = p[1];
            ushort8_t o;
            o[0] = f32_to_bf16_rne(v0.x);
            o[1] = f32_to_bf16_rne(v0.y);
            o[2] = f32_to_bf16_rne(v0.z);
            o[3] = f32_to_bf16_rne(v0.w);
            o[4] = f32_to_bf16_rne(v1.x);
            o[5] = f32_to_bf16_rne(v1.y);
            o[6] = f32_to_bf16_rne(v1.z);
            o[7] = f32_to_bf16_rne(v1.w);
            *(ushort8_t*)(xb + (size_t)i * 8) = o;
        }
    }
}

// ---------------------------------------------------------------------------
// GEMM: C[m][n] = sum_k A[m][k] * Bt[n][k] + bias[n]   (R9 verbatim — best)
// 128x256 tile, 8 waves = 4 regions (64x128) x 2 kk-roles (2.67 MFMA/read),
// triple-buffered LDS, ONE vmcnt(6)+lgkm(0)+barrier per K-tile, proven
// 0-conflict 128B-row swizzle, setprio around MFMA clusters, compiler-free
// regions. Epilogue combines kk pairs through the dead LDS buffers.
// ---------------------------------------------------------------------------
__global__ __launch_bounds__(512, 2) void gemm_bf16(
    const unsigned short* __restrict__ A,
    const unsigned short* __restrict__ Bt,
    const float* __restrict__ bias,
    float* __restrict__ C) {
    __shared__ __align__(16) char smem[147456];
    // A bufs: smem + buf*16384           (3 x 16 KiB)
    // B bufs: smem + 49152 + buf*32768   (3 x 32 KiB)
    // epilogue partials: smem + region*32768 (4 x 32 KiB, after K-loop)

    const int t      = threadIdx.x;
    const int lane   = t & 63;
    const int wave   = t >> 6;
    const int region = wave >> 1;    // 0..3 : 64x128 output region
    const int kkr    = wave & 1;     // 0/1  : K-half role
    const int rm     = region >> 1;  // 0..1 row block (x64)
    const int rn     = region & 1;   // 0..1 col block (x128)
    const int lrow   = lane & 15;
    const int lhi    = lane >> 4;

    // T1: XCD-aware swizzle (256 WGs, %8==0 -> bijective)
    const int wg  = blockIdx.x;
    const int swz = (wg & 7) * 32 + (wg >> 3);
    const int m0  = (swz >> 4) * BM;
    const int n0  = (swz & 15) * BN;

    // staging: linear LDS dest + inverse-swizzled global source
    auto stageA = [&](int buf, int tile, int c) {
        int row = c >> 3, p = c & 7;
        int l   = p ^ (row & 7);
        gload_lds16(A + (size_t)(m0 + row) * K_DIM + tile * BK + l * 8,
                    smem + buf * 16384 + c * 16);
    };
    auto stageB = [&](int buf, int tile, int c) {
        int row = c >> 3, p = c & 7;
        int l   = p ^ (row & 7);
        gload_lds16(Bt + (size_t)(n0 + row) * K_DIM + tile * BK + l * 8,
                    smem + 49152 + buf * 32768 + c * 16);
    };

    f32x4 acc[4][8];  // [mi][nj], this wave's kk-half partial
#pragma unroll
    for (int i = 0; i < 4; ++i)
#pragma unroll
        for (int j = 0; j < 8; ++j) acc[i][j] = (f32x4)0.0f;

    const int NT = K_DIM / BK;  // 64

    // prologue: tiles 0 and 1 fully staged (12 chunks/thread in flight)
    stageA(0, 0, t); stageA(0, 0, t + 512);
    stageB(0, 0, t); stageB(0, 0, t + 512);
    stageB(0, 0, t + 1024); stageB(0, 0, t + 1536);
    stageA(1, 1, t); stageA(1, 1, t + 512);
    stageB(1, 1, t); stageB(1, 1, t + 512);
    stageB(1, 1, t + 1024); stageB(1, 1, t + 1536);

    // fragment offsets (row&7 == lrow&7; proven 0-conflict pattern)
    const int rowOffA = (rm * 64 + lrow) * 128;          // + mi*2048, mi 0..3
    const int rowOffB = (rn * 128 + lrow) * 128;         // + nj*2048, nj 0..7
    const int sK = ((kkr * 4 + lhi) ^ (lrow & 7)) * 16;  // this wave's kk slot

    int bufC = 0, bufS = 2;
    for (int tau = 0; tau < NT; ++tau) {
        const int tile2 = (tau + 2 < NT) ? tau + 2 : NT - 1;

        // one wait + one barrier per K-tile; vmcnt NEVER drains to 0
        asm volatile("s_waitcnt vmcnt(6) lgkmcnt(0)" ::: "memory");
        __builtin_amdgcn_s_barrier();
        __builtin_amdgcn_sched_barrier(0);

        const char* bA = smem + bufC * 16384;
        const char* bB = smem + 49152 + bufC * 32768;

        // ---- P0: nj 0..3 ----
        bf16x8 af[4], bf[4];
#pragma unroll
        for (int mi = 0; mi < 4; ++mi)
            af[mi] = *(const bf16x8*)(bA + rowOffA + mi * 2048 + sK);
#pragma unroll
        for (int nj = 0; nj < 4; ++nj)
            bf[nj] = *(const bf16x8*)(bB + rowOffB + nj * 2048 + sK);
        stageA(bufS, tile2, t);
        stageA(bufS, tile2, t + 512);
        stageB(bufS, tile2, t);
        __builtin_amdgcn_s_setprio(1);
#pragma unroll
        for (int mi = 0; mi < 4; ++mi)
#pragma unroll
            for (int nj = 0; nj < 4; ++nj)
                acc[mi][nj] = __builtin_amdgcn_mfma_f32_16x16x32_bf16(
                    af[mi], bf[nj], acc[mi][nj], 0, 0, 0);
        __builtin_amdgcn_s_setprio(0);

        // ---- P1: nj 4..7 ----
        bf16x8 bg[4];
#pragma unroll
        for (int nj = 0; nj < 4; ++nj)
            bg[nj] = *(const bf16x8*)(bB + rowOffB + (nj + 4) * 2048 + sK);
        stageB(bufS, tile2, t + 512);
        stageB(bufS, tile2, t + 1024);
        stageB(bufS, tile2, t + 1536);
        __builtin_amdgcn_s_setprio(1);
#pragma unroll
        for (int mi = 0; mi < 4; ++mi)
#pragma unroll
            for (int nj = 0; nj < 4; ++nj)
                acc[mi][nj + 4] = __builtin_amdgcn_mfma_f32_16x16x32_bf16(
                    af[mi], bg[nj], acc[mi][nj + 4], 0, 0, 0);
        __builtin_amdgcn_s_setprio(0);

        bufC = (bufC == 2) ? 0 : bufC + 1;
        bufS = (bufS == 2) ? 0 : bufS + 1;
    }

    // ---- epilogue: combine kk pair via (dead) LDS, write C + bias ----
    __syncthreads();
    if (kkr == 1) {
#pragma unroll
        for (int mi = 0; mi < 4; ++mi)
#pragma unroll
            for (int nj = 0; nj < 8; ++nj)
                *(f32x4*)(smem + region * 32768 +
                          ((mi * 8 + nj) * 64 + lane) * 16) = acc[mi][nj];
    }
    __syncthreads();
    if (kkr == 0) {
        // C/D layout: col=lane&15, row=(lane>>4)*4+reg
#pragma unroll
        for (int nj = 0; nj < 8; ++nj) {
            int col  = n0 + rn * 128 + nj * 16 + lrow;
            float bv = bias[col];
#pragma unroll
            for (int mi = 0; mi < 4; ++mi) {
                f32x4 p = *(const f32x4*)(smem + region * 32768 +
                                          ((mi * 8 + nj) * 64 + lane) * 16);
                int rbase = m0 + rm * 64 + mi * 16 + lhi * 4;
#pragma unroll
                for (int r = 0; r < 4; ++r) {
                    C[(size_t)(rbase + r) * N_DIM + col] =
                        acc[mi][nj][r] + p[r] + bv;
                }
            }
        }
    }
}

// ---------------------------------------------------------------------------
extern "C" void kernel_launch(void* const* d_in, const int* in_sizes, int n_in,
                              void* d_out, int out_size, void* d_ws, size_t ws_size,
                              hipStream_t stream) {
    const float* x    = (const float*)d_in[0];
    const float* w    = (const float*)d_in[1];
    const float* bias = (const float*)d_in[2];
    float* out        = (float*)d_out;

    unsigned short* xb = (unsigned short*)d_ws;
    unsigned short* wt = (unsigned short*)((char*)d_ws +
                          (size_t)M_DIM * K_DIM * sizeof(unsigned short));

    prep_kernel<<<6144, 256, 0, stream>>>(x, xb, w, wt);

    dim3 ggrid((M_DIM / BM) * (N_DIM / BN));
    gemm_bf16<<<ggrid, 512, 0, stream>>>(xb, wt, bias, out);
}

// Round 14
// 89.214 us; speedup vs baseline: 1.0792x; 1.0073x over previous
//
#include <hip/hip_runtime.h>
#include <hip/hip_bf16.h>
#include <stdint.h>

#define M_DIM 2048
#define N_DIM 4096
#define K_DIM 4096

#define BM 128
#define BN 256
#define BK 64

typedef __bf16 bf16x8 __attribute__((ext_vector_type(8)));
typedef float f32x4 __attribute__((ext_vector_type(4)));
typedef unsigned short ushort8_t __attribute__((ext_vector_type(8)));

__device__ __forceinline__ unsigned short f32_to_bf16_rne(float f) {
    union { float f; uint32_t u; } cvt;
    cvt.f = f;
    uint32_t u = cvt.u;
    uint32_t r = (u + 0x7fffu + ((u >> 16) & 1u)) >> 16;
    return (unsigned short)r;
}

__device__ __forceinline__ void gload_lds16(const void* g, void* l) {
    __builtin_amdgcn_global_load_lds(
        (__attribute__((address_space(1))) const void*)g,
        (__attribute__((address_space(3))) void*)l,
        16, 0, 0);
}

// ---------------------------------------------------------------------------
// Fused prepass: blocks [0,4096) transpose+convert W (64x64 tiles);
// blocks [4096,6144) convert x f32->bf16.  (R13, at the BW floor.)
// ---------------------------------------------------------------------------
__global__ void prep_kernel(const float* __restrict__ x,
                            unsigned short* __restrict__ xb,
                            const float* __restrict__ W,
                            unsigned short* __restrict__ Wt) {
    __shared__ float tile[64][65];
    const int b = blockIdx.x;
    const int t = threadIdx.x;

    if (b < 4096) {
        const int n0 = (b & 63) * 64;
        const int k0 = (b >> 6) * 64;
        const int tx = t & 15;
        const int ty = t >> 4;

#pragma unroll
        for (int r = 0; r < 4; ++r) {
            int row = ty + 16 * r;
            float4 v = *(const float4*)(W + (size_t)(k0 + row) * N_DIM + n0 + tx * 4);
            tile[row][tx * 4 + 0] = v.x;
            tile[row][tx * 4 + 1] = v.y;
            tile[row][tx * 4 + 2] = v.z;
            tile[row][tx * 4 + 3] = v.w;
        }
        __syncthreads();
#pragma unroll
        for (int r = 0; r < 4; ++r) {
            int nrow = ty + 16 * r;
            ushort4 o;
            o.x = f32_to_bf16_rne(tile[tx * 4 + 0][nrow]);
            o.y = f32_to_bf16_rne(tile[tx * 4 + 1][nrow]);
            o.z = f32_to_bf16_rne(tile[tx * 4 + 2][nrow]);
            o.w = f32_to_bf16_rne(tile[tx * 4 + 3][nrow]);
            *(ushort4*)(Wt + (size_t)(n0 + nrow) * K_DIM + k0 + tx * 4) = o;
        }
    } else {
        const int n8 = M_DIM * K_DIM / 8;
        int i = (b - 4096) * blockDim.x + t;
        const int stride = 2048 * 256;
        for (; i < n8; i += stride) {
            const float4* p = (const float4*)(x + (size_t)i * 8);
            float4 v0 = p[0];
            float4 v1 = p[1];
            ushort8_t o;
            o[0] = f32_to_bf16_rne(v0.x);
            o[1] = f32_to_bf16_rne(v0.y);
            o[2] = f32_to_bf16_rne(v0.z);
            o[3] = f32_to_bf16_rne(v0.w);
            o[4] = f32_to_bf16_rne(v1.x);
            o[5] = f32_to_bf16_rne(v1.y);
            o[6] = f32_to_bf16_rne(v1.z);
            o[7] = f32_to_bf16_rne(v1.w);
            *(ushort8_t*)(xb + (size_t)i * 8) = o;
        }
    }
}

// ---------------------------------------------------------------------------
// GEMM: C[m][n] = sum_k A[m][k] * Bt[n][k] + bias[n]
// R9 structure (best: 66.4us / 44.7% MfmaUtil) with staging address
// arithmetic HOISTED to loop-invariant per-thread pointers (R4/R7-verified
// mapping): per tile each gload is pointer + uniform koff (~12 VALU vs ~36).
// Everything else byte-identical: 128x256 tile, 8 waves = 4 regions
// (64x128) x 2 kk-roles (2.67 MFMA/read), triple-buffered LDS, ONE
// vmcnt(6)+lgkm(0)+barrier per K-tile, proven 0-conflict 128B-row swizzle,
// setprio around MFMA clusters, kk-combine epilogue through dead LDS.
// ---------------------------------------------------------------------------
__global__ __launch_bounds__(512, 2) void gemm_bf16(
    const unsigned short* __restrict__ A,
    const unsigned short* __restrict__ Bt,
    const float* __restrict__ bias,
    float* __restrict__ C) {
    __shared__ __align__(16) char smem[147456];
    // A bufs: smem + buf*16384           (3 x 16 KiB)
    // B bufs: smem + 49152 + buf*32768   (3 x 32 KiB)
    // epilogue partials: smem + region*32768 (4 x 32 KiB, after K-loop)

    const int t      = threadIdx.x;
    const int lane   = t & 63;
    const int wave   = t >> 6;
    const int region = wave >> 1;    // 0..3 : 64x128 output region
    const int kkr    = wave & 1;     // 0/1  : K-half role
    const int rm     = region >> 1;  // 0..1 row block (x64)
    const int rn     = region & 1;   // 0..1 col block (x128)
    const int lrow   = lane & 15;
    const int lhi    = lane >> 4;

    // T1: XCD-aware swizzle (256 WGs, %8==0 -> bijective)
    const int wg  = blockIdx.x;
    const int swz = (wg & 7) * 32 + (wg >> 3);
    const int m0  = (swz >> 4) * BM;
    const int n0  = (swz & 15) * BN;

    // ---- loop-invariant staging pointers (inverse-swizzled global source,
    //      linear LDS dest) — R4/R7-verified mapping ----
    const int rowc = t >> 3;                  // 0..63
    const int lc   = (t & 7) ^ (rowc & 7);    // swizzled k-slot
    const unsigned short* gA0 = A  + (size_t)(m0 + rowc) * K_DIM + lc * 8;
    const unsigned short* gA1 = gA0 + (size_t)64  * K_DIM;   // rows 64..127
    const unsigned short* gB0 = Bt + (size_t)(n0 + rowc) * K_DIM + lc * 8;
    const unsigned short* gB1 = gB0 + (size_t)64  * K_DIM;
    const unsigned short* gB2 = gB0 + (size_t)128 * K_DIM;
    const unsigned short* gB3 = gB0 + (size_t)192 * K_DIM;
    char* dA = smem + t * 16;                 // + buf*16384 (+8192 unit 1)
    char* dB = smem + 49152 + t * 16;         // + buf*32768 (+8192k units)

    f32x4 acc[4][8];  // [mi][nj], this wave's kk-half partial
#pragma unroll
    for (int i = 0; i < 4; ++i)
#pragma unroll
        for (int j = 0; j < 8; ++j) acc[i][j] = (f32x4)0.0f;

    const int NT = K_DIM / BK;  // 64

    // prologue: tiles 0 and 1 fully staged (12 chunks/thread in flight)
    gload_lds16(gA0, dA);               gload_lds16(gA1, dA + 8192);
    gload_lds16(gB0, dB);               gload_lds16(gB1, dB + 8192);
    gload_lds16(gB2, dB + 16384);       gload_lds16(gB3, dB + 24576);
    gload_lds16(gA0 + BK, dA + 16384);  gload_lds16(gA1 + BK, dA + 24576);
    gload_lds16(gB0 + BK, dB + 32768);  gload_lds16(gB1 + BK, dB + 40960);
    gload_lds16(gB2 + BK, dB + 49152);  gload_lds16(gB3 + BK, dB + 57344);

    // fragment offsets (row&7 == lrow&7; proven 0-conflict pattern)
    const int rowOffA = (rm * 64 + lrow) * 128;          // + mi*2048, mi 0..3
    const int rowOffB = (rn * 128 + lrow) * 128;         // + nj*2048, nj 0..7
    const int sK = ((kkr * 4 + lhi) ^ (lrow & 7)) * 16;  // this wave's kk slot

    int bufC = 0, bufS = 2;
    for (int tau = 0; tau < NT; ++tau) {
        const size_t koff = (size_t)((tau + 2 < NT) ? tau + 2 : NT - 1) * BK;

        // one wait + one barrier per K-tile; vmcnt NEVER drains to 0
        asm volatile("s_waitcnt vmcnt(6) lgkmcnt(0)" ::: "memory");
        __builtin_amdgcn_s_barrier();
        __builtin_amdgcn_sched_barrier(0);

        const char* bA = smem + bufC * 16384;
        const char* bB = smem + 49152 + bufC * 32768;
        char* wA = dA + bufS * 16384;
        char* wB = dB + bufS * 32768;

        // ---- P0: nj 0..3 ----
        bf16x8 af[4], bf[4];
#pragma unroll
        for (int mi = 0; mi < 4; ++mi)
            af[mi] = *(const bf16x8*)(bA + rowOffA + mi * 2048 + sK);
#pragma unroll
        for (int nj = 0; nj < 4; ++nj)
            bf[nj] = *(const bf16x8*)(bB + rowOffB + nj * 2048 + sK);
        gload_lds16(gA0 + koff, wA);
        gload_lds16(gA1 + koff, wA + 8192);
        gload_lds16(gB0 + koff, wB);
        __builtin_amdgcn_s_setprio(1);
#pragma unroll
        for (int mi = 0; mi < 4; ++mi)
#pragma unroll
            for (int nj = 0; nj < 4; ++nj)
                acc[mi][nj] = __builtin_amdgcn_mfma_f32_16x16x32_bf16(
                    af[mi], bf[nj], acc[mi][nj], 0, 0, 0);
        __builtin_amdgcn_s_setprio(0);

        // ---- P1: nj 4..7 ----
        bf16x8 bg[4];
#pragma unroll
        for (int nj = 0; nj < 4; ++nj)
            bg[nj] = *(const bf16x8*)(bB + rowOffB + (nj + 4) * 2048 + sK);
        gload_lds16(gB1 + koff, wB + 8192);
        gload_lds16(gB2 + koff, wB + 16384);
        gload_lds16(gB3 + koff, wB + 24576);
        __builtin_amdgcn_s_setprio(1);
#pragma unroll
        for (int mi = 0; mi < 4; ++mi)
#pragma unroll
            for (int nj = 0; nj < 4; ++nj)
                acc[mi][nj + 4] = __builtin_amdgcn_mfma_f32_16x16x32_bf16(
                    af[mi], bg[nj], acc[mi][nj + 4], 0, 0, 0);
        __builtin_amdgcn_s_setprio(0);

        bufC = (bufC == 2) ? 0 : bufC + 1;
        bufS = (bufS == 2) ? 0 : bufS + 1;
    }

    // ---- epilogue: combine kk pair via (dead) LDS, write C + bias ----
    __syncthreads();
    if (kkr == 1) {
#pragma unroll
        for (int mi = 0; mi < 4; ++mi)
#pragma unroll
            for (int nj = 0; nj < 8; ++nj)
                *(f32x4*)(smem + region * 32768 +
                          ((mi * 8 + nj) * 64 + lane) * 16) = acc[mi][nj];
    }
    __syncthreads();
    if (kkr == 0) {
        // C/D layout: col=lane&15, row=(lane>>4)*4+reg
#pragma unroll
        for (int nj = 0; nj < 8; ++nj) {
            int col  = n0 + rn * 128 + nj * 16 + lrow;
            float bv = bias[col];
#pragma unroll
            for (int mi = 0; mi < 4; ++mi) {
                f32x4 p = *(const f32x4*)(smem + region * 32768 +
                                          ((mi * 8 + nj) * 64 + lane) * 16);
                int rbase = m0 + rm * 64 + mi * 16 + lhi * 4;
#pragma unroll
                for (int r = 0; r < 4; ++r) {
                    C[(size_t)(rbase + r) * N_DIM + col] =
                        acc[mi][nj][r] + p[r] + bv;
                }
            }
        }
    }
}

// ---------------------------------------------------------------------------
extern "C" void kernel_launch(void* const* d_in, const int* in_sizes, int n_in,
                              void* d_out, int out_size, void* d_ws, size_t ws_size,
                              hipStream_t stream) {
    const float* x    = (const float*)d_in[0];
    const float* w    = (const float*)d_in[1];
    const float* bias = (const float*)d_in[2];
    float* out        = (float*)d_out;

    unsigned short* xb = (unsigned short*)d_ws;
    unsigned short* wt = (unsigned short*)((char*)d_ws +
                          (size_t)M_DIM * K_DIM * sizeof(unsigned short));

    prep_kernel<<<6144, 256, 0, stream>>>(x, xb, w, wt);

    dim3 ggrid((M_DIM / BM) * (N_DIM / BN));
    gemm_bf16<<<ggrid, 512, 0, stream>>>(xb, wt, bias, out);
}